// Round 1
// baseline (641.350 us; speedup 1.0000x reference)
//
#include <hip/hip_runtime.h>

// SNN: conv1(3->64,3x3,p1)+LIF -> conv2(64->64,3x3,p1)+LIF -> FC(65536->10), sum over T=8
// LIF has no recurrence: spike = (conv_out >= 1.2f)
// out[b,o] = sum_i cnt[b,i]*wfc[o,i] + 8*bfc[o],  cnt[b,i] = sum_t spike2[t,b,i] (0..8)

#define NTHREADS 256

// ws layout (total ~8.55 MB, kept small since ws_size unknown)
static const size_t OFF_SPK = 0;                      // u8 [64][64][32][32] = 4 MiB (one timestep)
static const size_t OFF_CNT = 4u << 20;               // u8 [64][64][32][32] = 4 MiB
static const size_t OFF_W2T = 8u << 20;               // f32 [64ci][9][64co] = 147456 B
static const size_t OFF_W1T = (8u << 20) + 64*576*4;  // f32 [27][64co] = 6912 B

// Transpose weights to [k-index][co] so conv inner loops read contiguous co-vectors via s_load.
__global__ __launch_bounds__(NTHREADS) void kprep(
    const float* __restrict__ w1, const float* __restrict__ w2,
    float* __restrict__ w1T, float* __restrict__ w2T)
{
  int i = blockIdx.x * NTHREADS + threadIdx.x;
  if (i < 64*27)  { int co = i / 27;  int r = i - co*27;  w1T[r*64 + co] = w1[i]; }
  if (i < 64*576) { int co = i / 576; int r = i - co*576; w2T[r*64 + co] = w2[i]; }
}

// conv1 + LIF for one timestep t. grid = 64 b * 8 co-chunks(8 co). 256 thr, 4 adjacent px/thread.
__global__ __launch_bounds__(NTHREADS) void conv1_k(
    const float* __restrict__ x, const float* __restrict__ w1T,
    const float* __restrict__ b1, unsigned char* __restrict__ spk1, int t)
{
  const int b      = blockIdx.x >> 3;
  const int cobase = (blockIdx.x & 7) * 8;
  const int tid    = threadIdx.x;
  const int row    = tid >> 3;          // 0..31
  const int col4   = (tid & 7) * 4;     // 0,4,..,28

  __shared__ float lin[3][34][36];      // zero-padded input image
  float* lp = &lin[0][0][0];
  for (int i = tid; i < 3*34*36; i += NTHREADS) lp[i] = 0.f;
  __syncthreads();
  const float* xin = x + (size_t)(t*64 + b) * (3*1024);
  for (int i = tid; i < 768; i += NTHREADS) {      // 768 float4 = 3*1024 floats
    int ci = i >> 8, rem = i & 255, rr = rem >> 3, c4 = (rem & 7) * 4;
    float4 v = *(const float4*)(xin + ci*1024 + rr*32 + c4);
    lin[ci][rr+1][c4+1] = v.x; lin[ci][rr+1][c4+2] = v.y;
    lin[ci][rr+1][c4+3] = v.z; lin[ci][rr+1][c4+4] = v.w;
  }
  __syncthreads();

  float rin[3][3][6];                   // 3ci x 3rows x 6cols neighborhood for 4 px
  #pragma unroll
  for (int ci = 0; ci < 3; ci++)
    #pragma unroll
    for (int dr = 0; dr < 3; dr++)
      #pragma unroll
      for (int j = 0; j < 6; j++)
        rin[ci][dr][j] = lin[ci][row+dr][col4+j];   // input col = col4-1+j, +1 pad offset

  float acc[8][4];
  #pragma unroll
  for (int co = 0; co < 8; co++) {
    float bb = b1[cobase + co];
    #pragma unroll
    for (int p = 0; p < 4; p++) acc[co][p] = bb;
  }
  #pragma unroll
  for (int ci = 0; ci < 3; ci++)
    #pragma unroll
    for (int k = 0; k < 9; k++) {
      const int dr = k / 3, dc = k - dr*3;
      const float* wrow = w1T + (ci*9 + k)*64 + cobase;   // uniform -> s_load
      #pragma unroll
      for (int co = 0; co < 8; co++) {
        const float w = wrow[co];
        #pragma unroll
        for (int p = 0; p < 4; p++) acc[co][p] += w * rin[ci][dr][p + dc];
      }
    }

  unsigned char* sp = spk1 + (size_t)(b*64 + cobase)*1024 + row*32 + col4;
  #pragma unroll
  for (int co = 0; co < 8; co++) {
    uchar4 u;
    u.x = acc[co][0] >= 1.2f; u.y = acc[co][1] >= 1.2f;
    u.z = acc[co][2] >= 1.2f; u.w = acc[co][3] >= 1.2f;
    *(uchar4*)(sp + co*1024) = u;
  }
}

// conv2 + LIF + count-accumulate for one timestep.
// grid = 64 b * 4 row-tiles(8 rows) * 2 co-chunks(32 co) = 512 blocks, 256 thr = 32x8 px.
__global__ __launch_bounds__(NTHREADS) void conv2_k(
    const unsigned char* __restrict__ spk1, const float* __restrict__ w2T,
    const float* __restrict__ b2, unsigned char* __restrict__ cnt)
{
  const int bid    = blockIdx.x;
  const int cc     = bid & 1;
  const int rt     = (bid >> 1) & 3;
  const int b      = bid >> 3;
  const int cobase = cc * 32;
  const int r0     = rt * 8;
  const int tid    = threadIdx.x;
  const int r      = tid >> 5;   // 0..7
  const int c      = tid & 31;   // 0..31

  __shared__ unsigned char ls[64][10][40];   // [ci][row -1..+8][4B zero | 32 cols | 4B zero]
  for (int idx = tid; idx < 640; idx += NTHREADS) {
    int ci = idx / 10;
    int i  = idx - ci*10;
    int gr = r0 - 1 + i;
    unsigned int* dst = (unsigned int*)&ls[ci][i][0];
    if (gr >= 0 && gr < 32) {
      const uint4* src = (const uint4*)(spk1 + (size_t)((b*64 + ci)*32 + gr)*32);
      uint4 v0 = src[0], v1 = src[1];
      dst[0] = 0u;
      dst[1] = v0.x; dst[2] = v0.y; dst[3] = v0.z; dst[4] = v0.w;
      dst[5] = v1.x; dst[6] = v1.y; dst[7] = v1.z; dst[8] = v1.w;
      dst[9] = 0u;
    } else {
      #pragma unroll
      for (int q = 0; q < 10; q++) dst[q] = 0u;
    }
  }
  __syncthreads();

  float acc[32];
  #pragma unroll
  for (int co = 0; co < 32; co++) acc[co] = 0.f;

  for (int ci = 0; ci < 64; ci++) {
    float s[9];
    #pragma unroll
    for (int dr = 0; dr < 3; dr++)
      #pragma unroll
      for (int dc = 0; dc < 3; dc++)
        s[dr*3 + dc] = (float)ls[ci][r + dr][3 + c + dc];   // col c-1+dc at pad offset 4
    const float* wci = w2T + ci*576 + cobase;               // uniform -> s_load
    #pragma unroll
    for (int k = 0; k < 9; k++) {
      const float* wk = wci + k*64;
      #pragma unroll
      for (int co = 0; co < 32; co++)
        acc[co] += wk[co] * s[k];
    }
  }

  const int gr_out = r0 + r;
  unsigned char* cp = cnt + (size_t)((b*64 + cobase)*32 + gr_out)*32 + c;
  #pragma unroll
  for (int co = 0; co < 32; co++) {
    float v = acc[co] + b2[cobase + co];
    cp[co*1024] = (unsigned char)(cp[co*1024] + (v >= 1.2f ? 1 : 0));
  }
}

// FC: out[b,o] = sum_i cnt[b,i]*wfc[o,i] + 8*bfc[o]. grid = 4 i-chunks * 64 b.
__global__ __launch_bounds__(NTHREADS) void fc_k(
    const unsigned char* __restrict__ cnt, const float* __restrict__ wfc,
    const float* __restrict__ bfc, float* __restrict__ out)
{
  const int b     = blockIdx.x & 63;
  const int chunk = blockIdx.x >> 6;
  const int tid   = threadIdx.x;
  float acc[10];
  #pragma unroll
  for (int o = 0; o < 10; o++) acc[o] = 0.f;

  const int i4base = chunk*4096 + tid;     // units of 4 elements
  for (int w = 0; w < 16; w++) {
    int i4 = i4base + w*256;
    uchar4 cv = *(const uchar4*)(cnt + (size_t)b*65536 + i4*4);
    float c0 = cv.x, c1 = cv.y, c2 = cv.z, c3 = cv.w;
    #pragma unroll
    for (int o = 0; o < 10; o++) {
      float4 wv = *(const float4*)(wfc + (size_t)o*65536 + i4*4);
      acc[o] += wv.x*c0 + wv.y*c1 + wv.z*c2 + wv.w*c3;
    }
  }

  __shared__ float red[10][NTHREADS];
  #pragma unroll
  for (int o = 0; o < 10; o++) red[o][tid] = acc[o];
  __syncthreads();
  for (int off = NTHREADS/2; off > 0; off >>= 1) {
    if (tid < off) {
      #pragma unroll
      for (int o = 0; o < 10; o++) red[o][tid] += red[o][tid + off];
    }
    __syncthreads();
  }
  if (tid < 10) {
    float v = red[tid][0];
    if (chunk == 0) v += 8.0f * bfc[tid];
    atomicAdd(out + b*10 + tid, v);
  }
}

extern "C" void kernel_launch(void* const* d_in, const int* in_sizes, int n_in,
                              void* d_out, int out_size, void* d_ws, size_t ws_size,
                              hipStream_t stream)
{
  const float* x   = (const float*)d_in[0];
  const float* w1  = (const float*)d_in[1];
  const float* b1  = (const float*)d_in[2];
  const float* w2  = (const float*)d_in[3];
  const float* b2  = (const float*)d_in[4];
  const float* wfc = (const float*)d_in[5];
  const float* bfc = (const float*)d_in[6];
  float* out = (float*)d_out;

  unsigned char* ws   = (unsigned char*)d_ws;
  unsigned char* spk1 = ws + OFF_SPK;
  unsigned char* cnt  = ws + OFF_CNT;
  float* w2T = (float*)(ws + OFF_W2T);
  float* w1T = (float*)(ws + OFF_W1T);

  hipMemsetAsync(cnt, 0, 4u << 20, stream);
  hipMemsetAsync(out, 0, 64*10*sizeof(float), stream);
  kprep<<<144, NTHREADS, 0, stream>>>(w1, w2, w1T, w2T);
  for (int t = 0; t < 8; ++t) {
    conv1_k<<<512, NTHREADS, 0, stream>>>(x, w1T, b1, spk1, t);
    conv2_k<<<512, NTHREADS, 0, stream>>>(spk1, w2T, b2, cnt);
  }
  fc_k<<<256, NTHREADS, 0, stream>>>(cnt, wfc, bfc, out);
}

// Round 3
// 538.334 us; speedup vs baseline: 1.1914x; 1.1914x over previous
//
#include <hip/hip_runtime.h>
#include <hip/hip_bf16.h>

// SNN: conv1(3->64,3x3,p1)+LIF -> conv2(64->64,3x3,p1)+LIF -> FC(65536->10), sum over T=8
// LIF has no recurrence: spike = (conv_out >= 1.2f)
// conv2 via bf16 MFMA with 2-term split weights (w = hi + lo), spikes exact in bf16.

#define NT1 256

typedef __attribute__((ext_vector_type(8))) short bf16x8;
typedef __attribute__((ext_vector_type(4))) float f32x4;

// ws layout:
//  S   : bf16 [64b][34][34][64ci]   = 9,467,904 B (zero-padded ring)
//  cnt : u8   [64b][64ci][1024px]   = 4 MiB
//  wT2 : bf16 [2 halves][9 k][64co][64ci] = 147,456 B
//  w1T : f32  [27][64co]            = 6,912 B
static const size_t OFF_S   = 0;
static const size_t SZ_S    = (size_t)64 * 34 * 34 * 64 * 2;   // 9,467,904
static const size_t OFF_CNT = 9472000;                          // 256-aligned
static const size_t SZ_CNT  = 4u << 20;
static const size_t OFF_W2T = OFF_CNT + SZ_CNT;
static const size_t OFF_W1T = OFF_W2T + (size_t)2*9*64*64*2;

// Prep: w1 transpose to [k][co] (f32); w2 -> bf16 hi/lo split, layout [h][k=dr*3+dc][co][ci]
__global__ __launch_bounds__(NT1) void kprep(
    const float* __restrict__ w1, const float* __restrict__ w2,
    float* __restrict__ w1T, short* __restrict__ wT2)
{
  int i = blockIdx.x * NT1 + threadIdx.x;
  if (i < 64*27) { int co = i / 27; int r = i - co*27; w1T[r*64 + co] = w1[i]; }
  if (i < 64*576) {
    int co = i / 576, rem = i - co*576;
    int ci = rem / 9, s = rem - ci*9;
    float wv = w2[i];
    __hip_bfloat16 h = __float2bfloat16(wv);
    float hf = __bfloat162float(h);
    __hip_bfloat16 lo = __float2bfloat16(wv - hf);
    int off = s*4096 + co*64 + ci;
    wT2[off]         = *(short*)&h;
    wT2[36864 + off] = *(short*)&lo;
  }
}

// conv1 + LIF for timestep t -> padded bf16 spikes S[b][1+r][1+c][ci].
// grid = 64 b * 8 co-chunks(8 co). 256 thr, 4 adjacent px/thread.
__global__ __launch_bounds__(NT1) void conv1_k(
    const float* __restrict__ x, const float* __restrict__ w1T,
    const float* __restrict__ b1, short* __restrict__ S, int t)
{
  const int b      = blockIdx.x >> 3;
  const int cobase = (blockIdx.x & 7) * 8;
  const int tid    = threadIdx.x;
  const int row    = tid >> 3;          // 0..31
  const int col4   = (tid & 7) * 4;     // 0,4,..,28

  __shared__ float lin[3][34][36];      // zero-padded input image
  float* lp = &lin[0][0][0];
  for (int i = tid; i < 3*34*36; i += NT1) lp[i] = 0.f;
  __syncthreads();
  const float* xin = x + (size_t)(t*64 + b) * (3*1024);
  for (int i = tid; i < 768; i += NT1) {
    int ci = i >> 8, rem = i & 255, rr = rem >> 3, c4 = (rem & 7) * 4;
    float4 v = *(const float4*)(xin + ci*1024 + rr*32 + c4);
    lin[ci][rr+1][c4+1] = v.x; lin[ci][rr+1][c4+2] = v.y;
    lin[ci][rr+1][c4+3] = v.z; lin[ci][rr+1][c4+4] = v.w;
  }
  __syncthreads();

  float rin[3][3][6];
  #pragma unroll
  for (int ci = 0; ci < 3; ci++)
    #pragma unroll
    for (int dr = 0; dr < 3; dr++)
      #pragma unroll
      for (int j = 0; j < 6; j++)
        rin[ci][dr][j] = lin[ci][row+dr][col4+j];

  float acc[8][4];
  #pragma unroll
  for (int co = 0; co < 8; co++) {
    float bb = b1[cobase + co];
    #pragma unroll
    for (int p = 0; p < 4; p++) acc[co][p] = bb;
  }
  #pragma unroll
  for (int ci = 0; ci < 3; ci++)
    #pragma unroll
    for (int k = 0; k < 9; k++) {
      const int dr = k / 3, dc = k - dr*3;
      const float* wrow = w1T + (ci*9 + k)*64 + cobase;   // uniform -> s_load
      #pragma unroll
      for (int co = 0; co < 8; co++) {
        const float w = wrow[co];
        #pragma unroll
        for (int p = 0; p < 4; p++) acc[co][p] += w * rin[ci][dr][p + dc];
      }
    }

  // write spikes as bf16 (0x3F80 = 1.0bf16) at [b][row+1][col+1][ci], ci-contiguous
  short* sp = S + (size_t)b*(34*34*64) + ((size_t)(row+1)*34 + (col4+1))*64 + cobase;
  #pragma unroll
  for (int p = 0; p < 4; p++) {
    bf16x8 u;
    #pragma unroll
    for (int co = 0; co < 8; co++) u[co] = (acc[co][p] >= 1.2f) ? (short)0x3F80 : (short)0;
    *(bf16x8*)(sp + p*64) = u;
  }
}

// conv2 + LIF + count accumulate, pure MFMA (no LDS).
// grid = 64 b * 4 row-tiles(8 rows); 512 thr = 8 waves; wave = 1 image row (32px) x 64 co.
// K = 9 shifts * 64 ci, x2 for hi/lo weight split (A reused).
__global__ __launch_bounds__(512) void conv2_k(
    const short* __restrict__ S, const short* __restrict__ wT,
    const float* __restrict__ b2, unsigned char* __restrict__ cnt)
{
  const int bid = blockIdx.x;
  const int b   = bid >> 2;
  const int r0  = (bid & 3) << 3;
  const int tid = threadIdx.x;
  const int w   = tid >> 6;
  const int l   = tid & 63;
  const int lm  = l & 15;        // A row / B col / D col
  const int lk  = l >> 4;        // 0..3: k-group, D row group
  const int row = r0 + w;

  const short* Sb  = S + (size_t)b*(34*34*64);
  const int    ko0 = lk*8;

  f32x4 acc[2][4] = {};          // [mf: col-half][nf: co-quarter]

  #pragma unroll
  for (int s = 0; s < 9; ++s) {
    const int dr = s/3, dc = s - dr*3;
    const short* arow = Sb + ((size_t)(row+dr)*34 + (lm+dc))*64;
    const short* wrow = wT + s*4096 + lm*64;
    #pragma unroll
    for (int cih = 0; cih < 2; ++cih) {
      const int ko = cih*32 + ko0;
      bf16x8 a0 = *(const bf16x8*)(arow + ko);            // cols 0..15
      bf16x8 a1 = *(const bf16x8*)(arow + 16*64 + ko);    // cols 16..31
      #pragma unroll
      for (int nf = 0; nf < 4; ++nf) {
        bf16x8 bh = *(const bf16x8*)(wrow + nf*16*64 + ko);
        acc[0][nf] = __builtin_amdgcn_mfma_f32_16x16x32_bf16(a0, bh, acc[0][nf], 0, 0, 0);
        acc[1][nf] = __builtin_amdgcn_mfma_f32_16x16x32_bf16(a1, bh, acc[1][nf], 0, 0, 0);
      }
      #pragma unroll
      for (int nf = 0; nf < 4; ++nf) {
        bf16x8 bl = *(const bf16x8*)(wrow + 36864 + nf*16*64 + ko);
        acc[0][nf] = __builtin_amdgcn_mfma_f32_16x16x32_bf16(a0, bl, acc[0][nf], 0, 0, 0);
        acc[1][nf] = __builtin_amdgcn_mfma_f32_16x16x32_bf16(a1, bl, acc[1][nf], 0, 0, 0);
      }
    }
  }

  // D layout: lane holds co = nf*16+lm, px rows = 4*lk + e (cols within mf half-row)
  #pragma unroll
  for (int nf = 0; nf < 4; ++nf) {
    const float bias = b2[nf*16 + lm];
    unsigned int* cp = (unsigned int*)(cnt + ((size_t)(b*64 + nf*16 + lm))*1024 + row*32 + lk*4);
    #pragma unroll
    for (int mf = 0; mf < 2; ++mf) {
      unsigned int pack = 0;
      #pragma unroll
      for (int e = 0; e < 4; ++e) {
        float v = acc[mf][nf][e] + bias;
        pack |= (v >= 1.2f ? 1u : 0u) << (8*e);
      }
      cp[mf*4] += pack;   // counts <= 8, no inter-byte carry
    }
  }
}

// FC: out[b,o] = sum_i cnt[b,i]*wfc[o,i] + 8*bfc[o]. grid = 4 i-chunks * 64 b.
__global__ __launch_bounds__(NT1) void fc_k(
    const unsigned char* __restrict__ cnt, const float* __restrict__ wfc,
    const float* __restrict__ bfc, float* __restrict__ out)
{
  const int b     = blockIdx.x & 63;
  const int chunk = blockIdx.x >> 6;
  const int tid   = threadIdx.x;
  float acc[10];
  #pragma unroll
  for (int o = 0; o < 10; o++) acc[o] = 0.f;

  const int i4base = chunk*4096 + tid;
  for (int w = 0; w < 16; w++) {
    int i4 = i4base + w*256;
    uchar4 cv = *(const uchar4*)(cnt + (size_t)b*65536 + i4*4);
    float c0 = cv.x, c1 = cv.y, c2 = cv.z, c3 = cv.w;
    #pragma unroll
    for (int o = 0; o < 10; o++) {
      float4 wv = *(const float4*)(wfc + (size_t)o*65536 + i4*4);
      acc[o] += wv.x*c0 + wv.y*c1 + wv.z*c2 + wv.w*c3;
    }
  }

  __shared__ float red[10][NT1];
  #pragma unroll
  for (int o = 0; o < 10; o++) red[o][tid] = acc[o];
  __syncthreads();
  for (int off = NT1/2; off > 0; off >>= 1) {
    if (tid < off) {
      #pragma unroll
      for (int o = 0; o < 10; o++) red[o][tid] += red[o][tid + off];
    }
    __syncthreads();
  }
  if (tid < 10) {
    float v = red[tid][0];
    if (chunk == 0) v += 8.0f * bfc[tid];
    atomicAdd(out + b*10 + tid, v);
  }
}

extern "C" void kernel_launch(void* const* d_in, const int* in_sizes, int n_in,
                              void* d_out, int out_size, void* d_ws, size_t ws_size,
                              hipStream_t stream)
{
  const float* x   = (const float*)d_in[0];
  const float* w1  = (const float*)d_in[1];
  const float* b1  = (const float*)d_in[2];
  const float* w2  = (const float*)d_in[3];
  const float* b2  = (const float*)d_in[4];
  const float* wfc = (const float*)d_in[5];
  const float* bfc = (const float*)d_in[6];
  float* out = (float*)d_out;

  unsigned char* ws = (unsigned char*)d_ws;
  short* Sbuf = (short*)(ws + OFF_S);
  unsigned char* cnt = ws + OFF_CNT;
  short* wT2 = (short*)(ws + OFF_W2T);
  float* w1T = (float*)(ws + OFF_W1T);

  hipMemsetAsync(Sbuf, 0, SZ_S, stream);          // zero pad ring (interior rewritten per t)
  hipMemsetAsync(cnt, 0, SZ_CNT, stream);
  hipMemsetAsync(out, 0, 64*10*sizeof(float), stream);
  kprep<<<144, NT1, 0, stream>>>(w1, w2, w1T, wT2);
  for (int t = 0; t < 8; ++t) {
    conv1_k<<<512, NT1, 0, stream>>>(x, w1T, b1, Sbuf, t);
    conv2_k<<<256, 512, 0, stream>>>(Sbuf, wT2, b2, cnt);
  }
  fc_k<<<256, NT1, 0, stream>>>(cnt, wfc, bfc, out);
}

// Round 5
// 210.777 us; speedup vs baseline: 3.0428x; 2.5540x over previous
//
#include <hip/hip_runtime.h>
#include <hip/hip_bf16.h>

// SNN: conv1(3->64,3x3,p1)+LIF -> conv2(64->64,3x3,p1)+LIF -> FC(65536->10), sum T=8.
// LIF non-recurrent: spike = (pre >= 1.2f).
// conv1: bf16 MFMA 16x16x32, exact 4-term split (xh+xl)(wh+wl), register-im2col K=27->32
//        (k>=27 handled by ZERO WEIGHTS, A reads garbage safely).
// conv2: i8 MFMA 16x16x64, 2-term i8 weights (q1 + q2; s2=s1/254), spikes exact i8.
//        A-tile + B staged in LDS; all 8 timesteps in ONE launch; XCD-swizzled blocks.
// cnt accumulation: packed-u32 atomicAdd (counts<=8/byte, no carry).
// R5 fix: conv1 pixel loop covers ALL 32 rows (R4 only did rows 0..7 -> poison spikes).

typedef __attribute__((ext_vector_type(8))) short bf16x8;
typedef __attribute__((ext_vector_type(4))) float f32x4;
typedef __attribute__((ext_vector_type(4))) int   i32x4;

#define S1Q (5.5f/127.0f)       // q1 scale (max|N(0,1)| over 36864 < 5.5 w.p. ~1)
#define S2Q (S1Q/254.0f)        // q2 scale (resid <= s1/2 -> q2 <= 127)

// ws layout
static const size_t SZ_IMG  = 73984;                 // 34*34*64 i8, padded spike image
static const size_t OFF_S8  = 0;                     // [512 img][34][34][64] = 37,879,808
static const size_t OFF_CNT = 512*SZ_IMG;            // u8 [64b][64co][1024] = 4 MiB
static const size_t OFF_W1F = OFF_CNT + (4u<<20);    // bf16 [2][64co][32k] = 8192 B
static const size_t OFF_BQ  = OFF_W1F + 8192;        // i8 [2q][9s][64co][64ci] = 73,728 B

// ---- prep: conv1 weights bf16 hi/lo (k=s*3+ci, pad k>=27 with 0); conv2 weights 2-term i8
__global__ __launch_bounds__(256) void kprep(
    const float* __restrict__ w1, const float* __restrict__ w2,
    short* __restrict__ W1F, signed char* __restrict__ Bq)
{
  int i = blockIdx.x*256 + threadIdx.x;
  if (i < 4096) {                       // W1F[t2][co][k]
    int t2 = i >> 11, r = i & 2047, co = r >> 5, k = r & 31;
    short out = 0;
    if (k < 27) {
      int s = k/3, ci = k - s*3;
      float w = w1[co*27 + ci*9 + s];
      __hip_bfloat16 h = __float2bfloat16(w);
      if (t2 == 0) out = *(short*)&h;
      else { __hip_bfloat16 lo = __float2bfloat16(w - (float)h); out = *(short*)&lo; }
    }
    W1F[i] = out;
  }
  if (i < 36864) {                      // Bq[q][s][co][ci]
    int co = i/576, rem = i - co*576, ci = rem/9, s = rem - ci*9;
    float w = w2[i];
    int q1 = (int)roundf(w * (1.0f/S1Q)); q1 = q1 > 127 ? 127 : (q1 < -127 ? -127 : q1);
    float r1 = w - S1Q*(float)q1;
    int q2 = (int)roundf(r1 * (1.0f/S2Q)); q2 = q2 > 127 ? 127 : (q2 < -127 ? -127 : q2);
    int off = s*4096 + co*64 + ci;
    Bq[off] = (signed char)q1; Bq[36864 + off] = (signed char)q2;
  }
}

// ---- zero the pad ring of every spike image (interior rewritten by conv1)
__global__ __launch_bounds__(256) void rz(unsigned char* __restrict__ S8)
{
  unsigned char* base = S8 + (size_t)blockIdx.x * SZ_IMG;
  for (int i = threadIdx.x; i < 2112; i += 256) {
    int off;
    if (i < 544)       off = i*4;                       // top row
    else if (i < 1088) off = 33*2176 + (i-544)*4;       // bottom row
    else { int k = i - 1088; int r = 1 + (k>>5); int j = k & 31;
           off = r*2176 + ((j < 16) ? j*4 : 33*64 + (j-16)*4); }
    *(unsigned int*)(base + off) = 0u;
  }
}

// ---- conv1 + LIF, all timesteps: 512 blocks (1 img), 256 thr = 4 waves.
// Exact: (xh+xl)(wh+wl) -> 4 bf16 MFMA passes into one f32 acc.
// Wave-private bounce LDS (no barriers needed: same-wave DS ops are in-order).
__global__ __launch_bounds__(256, 2) void conv1_k(
    const float* __restrict__ x, const short* __restrict__ W1F,
    const float* __restrict__ b1, unsigned char* __restrict__ S8)
{
  const int img = blockIdx.x;                 // img%8 == XCD (natural order)
  const int tid = threadIdx.x;
  const int w   = tid >> 6;
  const int l   = tid & 63;
  const int lm  = l & 15, lk = l >> 4;

  __shared__ int xt4[7344];                   // xh[3][34][36] + xl[3][34][36] (u16 view)
  __shared__ i32x4 bnc4[4][16][4];            // per-wave spike bounce [16px][64co]
  unsigned short* xs = (unsigned short*)xt4;
  unsigned char*  bnc = (unsigned char*)bnc4;

  for (int i = tid; i < 7344; i += 256) xt4[i] = 0;
  __syncthreads();
  const float* xin = x + (size_t)img * 3072;
  for (int j = tid; j < 3072; j += 256) {
    int ci = j >> 10, r = (j >> 5) & 31, c = j & 31;
    float f = xin[j];
    __hip_bfloat16 h = __float2bfloat16(f);
    __hip_bfloat16 lo = __float2bfloat16(f - (float)h);
    int idx = ci*1224 + (r+1)*36 + (c+1);
    xs[idx] = *(unsigned short*)&h;
    xs[idx + 7344] = *(unsigned short*)&lo;
  }
  __syncthreads();

  // B fragments (hi/lo) + bias, per lane
  bf16x8 Wf[2][4];
  float  b1v[4];
  #pragma unroll
  for (int t2 = 0; t2 < 2; t2++)
    #pragma unroll
    for (int nf = 0; nf < 4; nf++)
      Wf[t2][nf] = *(const bf16x8*)(W1F + t2*2048 + (nf*16+lm)*32 + lk*8);
  #pragma unroll
  for (int nf = 0; nf < 4; nf++) b1v[nf] = b1[nf*16 + lm];

  // per-lane im2col gather offsets for k = lk*8+e (k = s*3+ci; k>=27 -> weight==0)
  int off16[8];
  #pragma unroll
  for (int e = 0; e < 8; e++) {
    int k = lk*8 + e;
    if (k < 27) { int s = k/3, ci = k - s*3, dr = s/3, dc = s - dr*3;
                  off16[e] = ci*1224 + dr*36 + dc; }
    else off16[e] = 0;
  }

  unsigned char* S8b = S8 + (size_t)img * SZ_IMG;
  for (int fi = 0; fi < 16; fi++) {          // 4 waves x 16 iters x 16 px = 1024 px
    const int pxF = w*16 + fi;               // (row, col-half)
    const int row = pxF >> 1, colh = pxF & 1;
    const int base16 = row*36 + colh*16 + lm;
    bf16x8 ah, al;
    #pragma unroll
    for (int e = 0; e < 8; e++) {
      int idx = base16 + off16[e];
      ah[e] = (short)xs[idx];
      al[e] = (short)xs[idx + 7344];
    }
    f32x4 acc[4] = {};
    #pragma unroll
    for (int nf = 0; nf < 4; nf++) {
      acc[nf] = __builtin_amdgcn_mfma_f32_16x16x32_bf16(ah, Wf[0][nf], acc[nf], 0,0,0);
      acc[nf] = __builtin_amdgcn_mfma_f32_16x16x32_bf16(al, Wf[0][nf], acc[nf], 0,0,0);
      acc[nf] = __builtin_amdgcn_mfma_f32_16x16x32_bf16(ah, Wf[1][nf], acc[nf], 0,0,0);
      acc[nf] = __builtin_amdgcn_mfma_f32_16x16x32_bf16(al, Wf[1][nf], acc[nf], 0,0,0);
    }
    // spikes -> wave-private bounce -> coalesced 16B stores (1 KB contiguous per wave)
    #pragma unroll
    for (int nf = 0; nf < 4; nf++)
      #pragma unroll
      for (int e4 = 0; e4 < 4; e4++) {
        float v = acc[nf][e4] + b1v[nf];
        bnc[w*1024 + (lk*4+e4)*64 + nf*16 + lm] = (v >= 1.2f) ? 1 : 0;
      }
    const int pxl = l >> 2, coq = l & 3;
    i32x4 sp = *(const i32x4*)(bnc + w*1024 + pxl*64 + coq*16);
    const int col = colh*16 + pxl;
    *(i32x4*)(S8b + ((row+1)*34 + (col+1))*64 + coq*16) = sp;
  }
}

// ---- conv2 + LIF + count, all timesteps. 2048 blocks, 512 thr = 8 waves.
// block = (img, rowhalf 16 rows, cohalf 32 co); wave = 2 rows x 32 co.
// LDS: A-tile 18x34x64 i8 (39168B) + B-half [2q][9s][32co][64ci] (36864B) = 76032B.
__global__ __launch_bounds__(512, 2) void conv2_k(
    const unsigned char* __restrict__ S8, const signed char* __restrict__ Bq,
    const float* __restrict__ b2, unsigned char* __restrict__ cnt)
{
  extern __shared__ __align__(16) unsigned char lds2[];
  const int j  = blockIdx.x;
  // XCD swizzle: j%8 == img%8 so conv2 hits the L2 conv1 wrote
  const int g = j >> 5, sub = (j >> 3) & 3, il = j & 7;
  const int img = g*8 + il;
  const int rh = sub >> 1, ch = sub & 1;
  const int b = img & 63;

  const int tid = threadIdx.x;
  const int w = tid >> 6, l = tid & 63;
  const int lm = l & 15, lk = l >> 4;

  // stage A (rows rh*16 .. rh*16+17 of padded img, contiguous) and B co-half
  {
    const unsigned char* Asrc = S8 + (size_t)img*SZ_IMG + (size_t)rh*34816;
    const signed char*   Bsrc = Bq;
    for (int i = tid; i < 4752; i += 512) {
      i32x4 v;
      if (i < 2448) v = *(const i32x4*)(Asrc + i*16);
      else { int c = i - 2448; int qs = c >> 7, inner = c & 127;
             v = *(const i32x4*)(Bsrc + qs*4096 + ch*2048 + inner*16); }
      *(i32x4*)(lds2 + i*16) = v;
    }
  }
  __syncthreads();

  float b2v[2];
  #pragma unroll
  for (int nf = 0; nf < 2; nf++) b2v[nf] = b2[ch*32 + nf*16 + lm];

  i32x4 acc1[4][2] = {};   // [aF][nf] for q1
  i32x4 acc2[4][2] = {};   // for q2

  #pragma unroll
  for (int s = 0; s < 9; s++) {
    const int dr = s/3, dc = s - dr*3;
    i32x4 Bf[2][2];
    #pragma unroll
    for (int q = 0; q < 2; q++)
      #pragma unroll
      for (int nf = 0; nf < 2; nf++)
        Bf[q][nf] = *(const i32x4*)(lds2 + 39168 + q*18432 + s*2048 + (nf*16+lm)*64 + lk*16);
    #pragma unroll
    for (int a = 0; a < 4; a++) {
      const int tr  = w*2 + (a>>1) + dr;          // 0..17
      const int col = (a&1)*16 + lm + dc;         // 0..33
      i32x4 Af = *(const i32x4*)(lds2 + tr*2176 + col*64 + lk*16);
      #pragma unroll
      for (int nf = 0; nf < 2; nf++) {
        acc1[a][nf] = __builtin_amdgcn_mfma_i32_16x16x64_i8(Af, Bf[0][nf], acc1[a][nf], 0,0,0);
        acc2[a][nf] = __builtin_amdgcn_mfma_i32_16x16x64_i8(Af, Bf[1][nf], acc2[a][nf], 0,0,0);
      }
    }
  }

  // epilogue: v = s1*A1 + s2*A2 + b2; spike bit -> packed u32 atomic count add
  #pragma unroll
  for (int a = 0; a < 4; a++) {
    const int row = rh*16 + w*2 + (a>>1);
    const int colb = (a&1)*16 + lk*4;
    #pragma unroll
    for (int nf = 0; nf < 2; nf++) {
      const int co = ch*32 + nf*16 + lm;
      unsigned int pack = 0;
      #pragma unroll
      for (int e = 0; e < 4; e++) {
        float v = S1Q*(float)acc1[a][nf][e] + S2Q*(float)acc2[a][nf][e] + b2v[nf];
        pack |= (v >= 1.2f ? 1u : 0u) << (8*e);
      }
      atomicAdd((unsigned int*)(cnt + ((size_t)(b*64 + co))*1024 + row*32 + colb), pack);
    }
  }
}

// ---- FC: out[b,o] = sum_i cnt[b,i]*wfc[o,i] + 8*bfc[o]
__global__ __launch_bounds__(256) void fc_k(
    const unsigned char* __restrict__ cnt, const float* __restrict__ wfc,
    const float* __restrict__ bfc, float* __restrict__ out)
{
  const int b = blockIdx.x & 63;
  const int chunk = blockIdx.x >> 6;
  const int tid = threadIdx.x;
  float acc[10];
  #pragma unroll
  for (int o = 0; o < 10; o++) acc[o] = 0.f;
  const int i4base = chunk*4096 + tid;
  for (int w = 0; w < 16; w++) {
    int i4 = i4base + w*256;
    uchar4 cv = *(const uchar4*)(cnt + (size_t)b*65536 + i4*4);
    float c0 = cv.x, c1 = cv.y, c2 = cv.z, c3 = cv.w;
    #pragma unroll
    for (int o = 0; o < 10; o++) {
      float4 wv = *(const float4*)(wfc + (size_t)o*65536 + i4*4);
      acc[o] += wv.x*c0 + wv.y*c1 + wv.z*c2 + wv.w*c3;
    }
  }
  __shared__ float red[10][256];
  #pragma unroll
  for (int o = 0; o < 10; o++) red[o][tid] = acc[o];
  __syncthreads();
  for (int off = 128; off > 0; off >>= 1) {
    if (tid < off) {
      #pragma unroll
      for (int o = 0; o < 10; o++) red[o][tid] += red[o][tid + off];
    }
    __syncthreads();
  }
  if (tid < 10) {
    float v = red[tid][0];
    if (chunk == 0) v += 8.0f * bfc[tid];
    atomicAdd(out + b*10 + tid, v);
  }
}

extern "C" void kernel_launch(void* const* d_in, const int* in_sizes, int n_in,
                              void* d_out, int out_size, void* d_ws, size_t ws_size,
                              hipStream_t stream)
{
  const float* x   = (const float*)d_in[0];
  const float* w1  = (const float*)d_in[1];
  const float* b1  = (const float*)d_in[2];
  const float* w2  = (const float*)d_in[3];
  const float* b2  = (const float*)d_in[4];
  const float* wfc = (const float*)d_in[5];
  const float* bfc = (const float*)d_in[6];
  float* out = (float*)d_out;

  unsigned char* ws  = (unsigned char*)d_ws;
  unsigned char* S8  = ws + OFF_S8;
  unsigned char* cnt = ws + OFF_CNT;
  short*         W1F = (short*)(ws + OFF_W1F);
  signed char*   Bq  = (signed char*)(ws + OFF_BQ);

  rz<<<512, 256, 0, stream>>>(S8);
  hipMemsetAsync(cnt, 0, 4u<<20, stream);
  hipMemsetAsync(out, 0, 64*10*sizeof(float), stream);
  kprep<<<144, 256, 0, stream>>>(w1, w2, W1F, Bq);
  conv1_k<<<512, 256, 0, stream>>>(x, W1F, b1, S8);
  conv2_k<<<2048, 512, 76032, stream>>>(S8, Bq, b2, cnt);
  fc_k<<<256, 256, 0, stream>>>(cnt, wfc, bfc, out);
}

// Round 6
// 154.286 us; speedup vs baseline: 4.1569x; 1.3661x over previous
//
#include <hip/hip_runtime.h>
#include <hip/hip_bf16.h>

// SNN: conv1(3->64,3x3,p1)+LIF -> conv2(64->64,3x3,p1)+LIF -> FC(65536->10), sum T=8.
// LIF non-recurrent: spike = (pre >= 1.2f).
// conv1: bf16 MFMA 16x16x32, exact 4-term split (xh+xl)(wh+wl), register-im2col K=27->32.
// conv2: i8 MFMA 16x16x64, 2-term i8 weights (q1 + q2; s2=s1/254), spikes exact i8.
//        R6: t-loop INSIDE block (256 blocks b/rh/ch); counts in registers (NO atomics);
//        B-fragments persistent in VGPRs; A-tile LDS with chunk-XOR swizzle
//        (c ^= (col>>1)&3, applied at conv1 store, undone at conv2 read).

typedef __attribute__((ext_vector_type(8))) short bf16x8;
typedef __attribute__((ext_vector_type(4))) float f32x4;
typedef __attribute__((ext_vector_type(4))) int   i32x4;

#define S1Q (5.5f/127.0f)       // q1 scale (max|N(0,1)| over 36864 < 5.5 w.p. ~1)
#define S2Q (S1Q/254.0f)        // q2 scale (resid <= s1/2 -> q2 <= 127)

// ws layout
static const size_t SZ_IMG  = 73984;                 // 34*34*64 i8, padded spike image
static const size_t OFF_S8  = 0;                     // [512 img][34][34][64] = 37,879,808
static const size_t OFF_CNT = 512*SZ_IMG;            // u8 [64b][64co][1024] = 4 MiB
static const size_t OFF_W1F = OFF_CNT + (4u<<20);    // bf16 [2][64co][32k] = 8192 B
static const size_t OFF_BQ  = OFF_W1F + 8192;        // i8 [2q][9s][64co][64ci] = 73,728 B

// ---- prep: conv1 weights bf16 hi/lo (k=s*3+ci, pad k>=27 with 0); conv2 weights 2-term i8
__global__ __launch_bounds__(256) void kprep(
    const float* __restrict__ w1, const float* __restrict__ w2,
    short* __restrict__ W1F, signed char* __restrict__ Bq)
{
  int i = blockIdx.x*256 + threadIdx.x;
  if (i < 4096) {                       // W1F[t2][co][k]
    int t2 = i >> 11, r = i & 2047, co = r >> 5, k = r & 31;
    short out = 0;
    if (k < 27) {
      int s = k/3, ci = k - s*3;
      float w = w1[co*27 + ci*9 + s];
      __hip_bfloat16 h = __float2bfloat16(w);
      if (t2 == 0) out = *(short*)&h;
      else { __hip_bfloat16 lo = __float2bfloat16(w - (float)h); out = *(short*)&lo; }
    }
    W1F[i] = out;
  }
  if (i < 36864) {                      // Bq[q][s][co][ci]
    int co = i/576, rem = i - co*576, ci = rem/9, s = rem - ci*9;
    float w = w2[i];
    int q1 = (int)roundf(w * (1.0f/S1Q)); q1 = q1 > 127 ? 127 : (q1 < -127 ? -127 : q1);
    float r1 = w - S1Q*(float)q1;
    int q2 = (int)roundf(r1 * (1.0f/S2Q)); q2 = q2 > 127 ? 127 : (q2 < -127 ? -127 : q2);
    int off = s*4096 + co*64 + ci;
    Bq[off] = (signed char)q1; Bq[36864 + off] = (signed char)q2;
  }
}

// ---- zero the pad ring of every spike image (zeros are swizzle-invariant)
__global__ __launch_bounds__(256) void rz(unsigned char* __restrict__ S8)
{
  unsigned char* base = S8 + (size_t)blockIdx.x * SZ_IMG;
  for (int i = threadIdx.x; i < 2112; i += 256) {
    int off;
    if (i < 544)       off = i*4;                       // top row
    else if (i < 1088) off = 33*2176 + (i-544)*4;       // bottom row
    else { int k = i - 1088; int r = 1 + (k>>5); int j = k & 31;
           off = r*2176 + ((j < 16) ? j*4 : 33*64 + (j-16)*4); }
    *(unsigned int*)(base + off) = 0u;
  }
}

// ---- conv1 + LIF, all timesteps: 512 blocks (1 img), 256 thr = 4 waves.
// Exact: (xh+xl)(wh+wl) -> 4 bf16 MFMA passes into one f32 acc.
// Stores spikes with chunk-XOR swizzle (c ^= ((padded_col>>1)&3)).
__global__ __launch_bounds__(256, 2) void conv1_k(
    const float* __restrict__ x, const short* __restrict__ W1F,
    const float* __restrict__ b1, unsigned char* __restrict__ S8)
{
  const int img = blockIdx.x;                 // img%8 == XCD (natural order)
  const int tid = threadIdx.x;
  const int w   = tid >> 6;
  const int l   = tid & 63;
  const int lm  = l & 15, lk = l >> 4;

  __shared__ int xt4[7344];                   // xh[3][34][36] + xl[3][34][36] (u16 view)
  __shared__ i32x4 bnc4[4][16][4];            // per-wave spike bounce [16px][64co]
  unsigned short* xs = (unsigned short*)xt4;
  unsigned char*  bnc = (unsigned char*)bnc4;

  for (int i = tid; i < 7344; i += 256) xt4[i] = 0;
  __syncthreads();
  const float* xin = x + (size_t)img * 3072;
  for (int j = tid; j < 3072; j += 256) {
    int ci = j >> 10, r = (j >> 5) & 31, c = j & 31;
    float f = xin[j];
    __hip_bfloat16 h = __float2bfloat16(f);
    __hip_bfloat16 lo = __float2bfloat16(f - (float)h);
    int idx = ci*1224 + (r+1)*36 + (c+1);
    xs[idx] = *(unsigned short*)&h;
    xs[idx + 7344] = *(unsigned short*)&lo;
  }
  __syncthreads();

  // B fragments (hi/lo) + bias, per lane
  bf16x8 Wf[2][4];
  float  b1v[4];
  #pragma unroll
  for (int t2 = 0; t2 < 2; t2++)
    #pragma unroll
    for (int nf = 0; nf < 4; nf++)
      Wf[t2][nf] = *(const bf16x8*)(W1F + t2*2048 + (nf*16+lm)*32 + lk*8);
  #pragma unroll
  for (int nf = 0; nf < 4; nf++) b1v[nf] = b1[nf*16 + lm];

  // per-lane im2col gather offsets for k = lk*8+e (k = s*3+ci; k>=27 -> weight==0)
  int off16[8];
  #pragma unroll
  for (int e = 0; e < 8; e++) {
    int k = lk*8 + e;
    if (k < 27) { int s = k/3, ci = k - s*3, dr = s/3, dc = s - dr*3;
                  off16[e] = ci*1224 + dr*36 + dc; }
    else off16[e] = 0;
  }

  unsigned char* S8b = S8 + (size_t)img * SZ_IMG;
  for (int fi = 0; fi < 16; fi++) {          // 4 waves x 16 iters x 16 px = 1024 px
    const int pxF = w*16 + fi;               // (row, col-half)
    const int row = pxF >> 1, colh = pxF & 1;
    const int base16 = row*36 + colh*16 + lm;
    bf16x8 ah, al;
    #pragma unroll
    for (int e = 0; e < 8; e++) {
      int idx = base16 + off16[e];
      ah[e] = (short)xs[idx];
      al[e] = (short)xs[idx + 7344];
    }
    f32x4 acc[4] = {};
    #pragma unroll
    for (int nf = 0; nf < 4; nf++) {
      acc[nf] = __builtin_amdgcn_mfma_f32_16x16x32_bf16(ah, Wf[0][nf], acc[nf], 0,0,0);
      acc[nf] = __builtin_amdgcn_mfma_f32_16x16x32_bf16(al, Wf[0][nf], acc[nf], 0,0,0);
      acc[nf] = __builtin_amdgcn_mfma_f32_16x16x32_bf16(ah, Wf[1][nf], acc[nf], 0,0,0);
      acc[nf] = __builtin_amdgcn_mfma_f32_16x16x32_bf16(al, Wf[1][nf], acc[nf], 0,0,0);
    }
    // spikes -> wave-private bounce -> coalesced 16B stores (1 KB contiguous per wave)
    #pragma unroll
    for (int nf = 0; nf < 4; nf++)
      #pragma unroll
      for (int e4 = 0; e4 < 4; e4++) {
        float v = acc[nf][e4] + b1v[nf];
        bnc[w*1024 + (lk*4+e4)*64 + nf*16 + lm] = (v >= 1.2f) ? 1 : 0;
      }
    const int pxl = l >> 2, coq = l & 3;
    i32x4 sp = *(const i32x4*)(bnc + w*1024 + pxl*64 + coq*16);
    const int colp = colh*16 + pxl + 1;               // padded col
    const int cq = coq ^ ((colp >> 1) & 3);           // chunk swizzle
    *(i32x4*)(S8b + ((row+1)*34 + colp)*64 + cq*16) = sp;
  }
}

// ---- conv2 + LIF + count, t-loop inside. 256 blocks (b, rh, ch), 512 thr = 8 waves.
// B-frags persistent in VGPRs (loaded once from global); A-tile in LDS per t (swizzled);
// counts accumulate in registers; single plain store (no atomics, no cnt memset).
__global__ __launch_bounds__(512, 2) void conv2_k(
    const unsigned char* __restrict__ S8, const signed char* __restrict__ Bq,
    const float* __restrict__ b2, unsigned char* __restrict__ cnt)
{
  __shared__ __align__(16) unsigned char Abuf[40960];   // 18 rows x 34 col x 64ci (+tail)
  const int j = blockIdx.x;
  const int xcd = j & 7, g = j >> 3;
  const int b   = ((g & 7) << 3) | xcd;     // b%8 == j%8 == conv1's XCD for img t*64+b
  const int sub = g >> 3;                   // 0..3
  const int rh  = sub >> 1, ch = sub & 1;

  const int tid = threadIdx.x;
  const int w = tid >> 6, l = tid & 63;
  const int lm = l & 15, lk = l >> 4;

  // persistent B fragments: [q][s][nf], 36 x i32x4 = 144 VGPR (L2-broadcast reads)
  i32x4 Bf[2][9][2];
  #pragma unroll
  for (int q = 0; q < 2; q++)
    #pragma unroll
    for (int s = 0; s < 9; s++)
      #pragma unroll
      for (int nf = 0; nf < 2; nf++)
        Bf[q][s][nf] = *(const i32x4*)(Bq + q*36864 + s*4096 + (ch*32+nf*16+lm)*64 + lk*16);

  const float b2v[2] = { b2[ch*32 + lm], b2[ch*32 + 16 + lm] };

  unsigned int cntp[4][2] = {};             // packed 4-px counts per (a, nf)

  for (int t = 0; t < 8; t++) {
    // stage A-tile: rows rh*16 .. rh*16+17 of padded img (linear copy keeps swizzle);
    // 2560 chunks (112 tail garbage, never read) = 5 per thread, uniform.
    const unsigned char* As = S8 + (size_t)(t*64 + b)*SZ_IMG + (size_t)rh*34816;
    #pragma unroll
    for (int it = 0; it < 5; it++) {
      const int idx = it*512 + tid;
      *(i32x4*)(Abuf + idx*16) = *(const i32x4*)(As + (size_t)idx*16);
    }
    __syncthreads();

    i32x4 acc1[4][2] = {}, acc2[4][2] = {};
    #pragma unroll
    for (int s = 0; s < 9; s++) {
      const int dr = s/3, dc = s - dr*3;
      #pragma unroll
      for (int a = 0; a < 4; a++) {
        const int tr = w*2 + (a>>1) + dr;             // 0..17
        const int cp = ((a&1)<<4) + lm + dc;          // padded col 0..33
        i32x4 Af = *(const i32x4*)(Abuf + tr*2176 + cp*64 + ((lk ^ ((cp>>1)&3))<<4));
        #pragma unroll
        for (int nf = 0; nf < 2; nf++) {
          acc1[a][nf] = __builtin_amdgcn_mfma_i32_16x16x64_i8(Af, Bf[0][s][nf], acc1[a][nf],0,0,0);
          acc2[a][nf] = __builtin_amdgcn_mfma_i32_16x16x64_i8(Af, Bf[1][s][nf], acc2[a][nf],0,0,0);
        }
      }
    }

    #pragma unroll
    for (int a = 0; a < 4; a++)
      #pragma unroll
      for (int nf = 0; nf < 2; nf++) {
        unsigned int p = 0;
        #pragma unroll
        for (int e = 0; e < 4; e++) {
          float v = S1Q*(float)acc1[a][nf][e] + S2Q*(float)acc2[a][nf][e] + b2v[nf];
          p |= (v >= 1.2f ? 1u : 0u) << (8*e);
        }
        cntp[a][nf] += p;                   // counts <= 8 per byte, no carry
      }
    __syncthreads();                        // all waves done reading Abuf before next stage
  }

  // single plain store per u32 (each (b,co,px-quad) owned by exactly one lane)
  #pragma unroll
  for (int a = 0; a < 4; a++) {
    const int row  = rh*16 + w*2 + (a>>1);
    const int colb = ((a&1)<<4) + lk*4;
    #pragma unroll
    for (int nf = 0; nf < 2; nf++) {
      const int co = ch*32 + nf*16 + lm;
      *(unsigned int*)(cnt + ((size_t)(b*64 + co))*1024 + row*32 + colb) = cntp[a][nf];
    }
  }
}

// ---- FC: out[b,o] = sum_i cnt[b,i]*wfc[o,i] + 8*bfc[o]
__global__ __launch_bounds__(256) void fc_k(
    const unsigned char* __restrict__ cnt, const float* __restrict__ wfc,
    const float* __restrict__ bfc, float* __restrict__ out)
{
  const int b = blockIdx.x & 63;
  const int chunk = blockIdx.x >> 6;
  const int tid = threadIdx.x;
  float acc[10];
  #pragma unroll
  for (int o = 0; o < 10; o++) acc[o] = 0.f;
  const int i4base = chunk*4096 + tid;
  for (int w = 0; w < 16; w++) {
    int i4 = i4base + w*256;
    uchar4 cv = *(const uchar4*)(cnt + (size_t)b*65536 + i4*4);
    float c0 = cv.x, c1 = cv.y, c2 = cv.z, c3 = cv.w;
    #pragma unroll
    for (int o = 0; o < 10; o++) {
      float4 wv = *(const float4*)(wfc + (size_t)o*65536 + i4*4);
      acc[o] += wv.x*c0 + wv.y*c1 + wv.z*c2 + wv.w*c3;
    }
  }
  __shared__ float red[10][256];
  #pragma unroll
  for (int o = 0; o < 10; o++) red[o][tid] = acc[o];
  __syncthreads();
  for (int off = 128; off > 0; off >>= 1) {
    if (tid < off) {
      #pragma unroll
      for (int o = 0; o < 10; o++) red[o][tid] += red[o][tid + off];
    }
    __syncthreads();
  }
  if (tid < 10) {
    float v = red[tid][0];
    if (chunk == 0) v += 8.0f * bfc[tid];
    atomicAdd(out + b*10 + tid, v);
  }
}

extern "C" void kernel_launch(void* const* d_in, const int* in_sizes, int n_in,
                              void* d_out, int out_size, void* d_ws, size_t ws_size,
                              hipStream_t stream)
{
  const float* x   = (const float*)d_in[0];
  const float* w1  = (const float*)d_in[1];
  const float* b1  = (const float*)d_in[2];
  const float* w2  = (const float*)d_in[3];
  const float* b2  = (const float*)d_in[4];
  const float* wfc = (const float*)d_in[5];
  const float* bfc = (const float*)d_in[6];
  float* out = (float*)d_out;

  unsigned char* ws  = (unsigned char*)d_ws;
  unsigned char* S8  = ws + OFF_S8;
  unsigned char* cnt = ws + OFF_CNT;
  short*         W1F = (short*)(ws + OFF_W1F);
  signed char*   Bq  = (signed char*)(ws + OFF_BQ);

  rz<<<512, 256, 0, stream>>>(S8);
  hipMemsetAsync(out, 0, 64*10*sizeof(float), stream);
  kprep<<<144, 256, 0, stream>>>(w1, w2, W1F, Bq);
  conv1_k<<<512, 256, 0, stream>>>(x, W1F, b1, S8);
  conv2_k<<<256, 512, 0, stream>>>(S8, Bq, b2, cnt);
  fc_k<<<256, 256, 0, stream>>>(cnt, wfc, bfc, out);
}

// Round 7
// 143.666 us; speedup vs baseline: 4.4642x; 1.0739x over previous
//
#include <hip/hip_runtime.h>
#include <hip/hip_bf16.h>

// SNN: conv1(3->64,3x3,p1)+LIF -> conv2(64->64,3x3,p1)+LIF -> FC(65536->10), sum T=8.
// LIF non-recurrent: spike = (pre >= 1.2f).
// conv1: bf16 MFMA 16x16x32, exact 4-term split (xh+xl)(wh+wl), register-im2col K=27->32.
// conv2: i8 MFMA 16x16x64, 2-term i8 weights (q1+q2; s2=s1/254), spikes exact i8.
// R7: unpadded S8 (64KB/img, L2-resident per XCD); conv2 double-buffers the A-tile via
//     global_load_lds (prefetch t+1 under compute t); padding lives in LDS (zeroed once);
//     cnt written via LDS bounce as full 16B lines. rz kernel deleted.

typedef __attribute__((ext_vector_type(8))) short bf16x8;
typedef __attribute__((ext_vector_type(4))) float f32x4;
typedef __attribute__((ext_vector_type(4))) int   i32x4;

#define S1Q (5.5f/127.0f)       // q1 scale (max|N(0,1)| over 36864 < 5.5 w.p. ~1)
#define S2Q (S1Q/254.0f)        // q2 scale (resid <= s1/2 -> q2 <= 127)

// ws layout
static const size_t SZ_IMG  = 65536;                 // 32*32*64 i8, unpadded spike image
static const size_t OFF_S8  = 0;                     // [512 img] = 33,554,432 B
static const size_t OFF_CNT = 512*SZ_IMG;            // u8 [64b][64co][1024] = 4 MiB
static const size_t OFF_W1F = OFF_CNT + (4u<<20);    // bf16 [2][64co][32k] = 8192 B
static const size_t OFF_BQ  = OFF_W1F + 8192;        // i8 [2q][9s][64co][64ci] = 73,728 B

// chunk swizzle (bank-conflict-free A reads; defined on padded col = gcol+1)
#define SWZ(cp) (((cp) >> 1) & 3)

__device__ __forceinline__ void gl_lds16(const void* g, void* l) {
  __builtin_amdgcn_global_load_lds(
      (const __attribute__((address_space(1))) unsigned int*)g,
      (__attribute__((address_space(3))) unsigned int*)l, 16, 0, 0);
}

// ---- prep: conv1 weights bf16 hi/lo (k=s*3+ci, pad k>=27 with 0); conv2 weights 2-term i8
__global__ __launch_bounds__(256) void kprep(
    const float* __restrict__ w1, const float* __restrict__ w2,
    short* __restrict__ W1F, signed char* __restrict__ Bq)
{
  int i = blockIdx.x*256 + threadIdx.x;
  if (i < 4096) {                       // W1F[t2][co][k]
    int t2 = i >> 11, r = i & 2047, co = r >> 5, k = r & 31;
    short out = 0;
    if (k < 27) {
      int s = k/3, ci = k - s*3;
      float w = w1[co*27 + ci*9 + s];
      __hip_bfloat16 h = __float2bfloat16(w);
      if (t2 == 0) out = *(short*)&h;
      else { __hip_bfloat16 lo = __float2bfloat16(w - (float)h); out = *(short*)&lo; }
    }
    W1F[i] = out;
  }
  if (i < 36864) {                      // Bq[q][s][co][ci]
    int co = i/576, rem = i - co*576, ci = rem/9, s = rem - ci*9;
    float w = w2[i];
    int q1 = (int)roundf(w * (1.0f/S1Q)); q1 = q1 > 127 ? 127 : (q1 < -127 ? -127 : q1);
    float r1 = w - S1Q*(float)q1;
    int q2 = (int)roundf(r1 * (1.0f/S2Q)); q2 = q2 > 127 ? 127 : (q2 < -127 ? -127 : q2);
    int off = s*4096 + co*64 + ci;
    Bq[off] = (signed char)q1; Bq[36864 + off] = (signed char)q2;
  }
}

// ---- conv1 + LIF, all timesteps: 512 blocks (1 img), 256 thr = 4 waves.
// Exact: (xh+xl)(wh+wl) -> 4 bf16 MFMA passes into one f32 acc.
// Stores UNPADDED spikes with chunk-XOR swizzle cq = coq ^ SWZ(gcol+1).
__global__ __launch_bounds__(256, 2) void conv1_k(
    const float* __restrict__ x, const short* __restrict__ W1F,
    const float* __restrict__ b1, unsigned char* __restrict__ S8)
{
  const int img = blockIdx.x;                 // img%8 == b%8 == XCD (round-robin assumption)
  const int tid = threadIdx.x;
  const int w   = tid >> 6;
  const int l   = tid & 63;
  const int lm  = l & 15, lk = l >> 4;

  __shared__ int xt4[7344];                   // xh[3][34][36] + xl[3][34][36] (u16 view)
  __shared__ i32x4 bnc4[4][16][4];            // per-wave spike bounce [16px][64co]
  unsigned short* xs = (unsigned short*)xt4;
  unsigned char*  bnc = (unsigned char*)bnc4;

  for (int i = tid; i < 7344; i += 256) xt4[i] = 0;
  __syncthreads();
  const float* xin = x + (size_t)img * 3072;
  for (int j = tid; j < 3072; j += 256) {
    int ci = j >> 10, r = (j >> 5) & 31, c = j & 31;
    float f = xin[j];
    __hip_bfloat16 h = __float2bfloat16(f);
    __hip_bfloat16 lo = __float2bfloat16(f - (float)h);
    int idx = ci*1224 + (r+1)*36 + (c+1);
    xs[idx] = *(unsigned short*)&h;
    xs[idx + 7344] = *(unsigned short*)&lo;
  }
  __syncthreads();

  // B fragments (hi/lo) + bias, per lane
  bf16x8 Wf[2][4];
  float  b1v[4];
  #pragma unroll
  for (int t2 = 0; t2 < 2; t2++)
    #pragma unroll
    for (int nf = 0; nf < 4; nf++)
      Wf[t2][nf] = *(const bf16x8*)(W1F + t2*2048 + (nf*16+lm)*32 + lk*8);
  #pragma unroll
  for (int nf = 0; nf < 4; nf++) b1v[nf] = b1[nf*16 + lm];

  // per-lane im2col gather offsets for k = lk*8+e (k = s*3+ci; k>=27 -> weight==0)
  int off16[8];
  #pragma unroll
  for (int e = 0; e < 8; e++) {
    int k = lk*8 + e;
    if (k < 27) { int s = k/3, ci = k - s*3, dr = s/3, dc = s - dr*3;
                  off16[e] = ci*1224 + dr*36 + dc; }
    else off16[e] = 0;
  }

  unsigned char* S8b = S8 + (size_t)img * SZ_IMG;
  for (int fi = 0; fi < 16; fi++) {          // 4 waves x 16 iters x 16 px = 1024 px
    const int pxF = w*16 + fi;               // (row, col-half)
    const int row = pxF >> 1, colh = pxF & 1;
    const int base16 = row*36 + colh*16 + lm;
    bf16x8 ah, al;
    #pragma unroll
    for (int e = 0; e < 8; e++) {
      int idx = base16 + off16[e];
      ah[e] = (short)xs[idx];
      al[e] = (short)xs[idx + 7344];
    }
    f32x4 acc[4] = {};
    #pragma unroll
    for (int nf = 0; nf < 4; nf++) {
      acc[nf] = __builtin_amdgcn_mfma_f32_16x16x32_bf16(ah, Wf[0][nf], acc[nf], 0,0,0);
      acc[nf] = __builtin_amdgcn_mfma_f32_16x16x32_bf16(al, Wf[0][nf], acc[nf], 0,0,0);
      acc[nf] = __builtin_amdgcn_mfma_f32_16x16x32_bf16(ah, Wf[1][nf], acc[nf], 0,0,0);
      acc[nf] = __builtin_amdgcn_mfma_f32_16x16x32_bf16(al, Wf[1][nf], acc[nf], 0,0,0);
    }
    // spikes -> wave-private bounce -> coalesced 16B stores (1 KB contiguous per wave)
    #pragma unroll
    for (int nf = 0; nf < 4; nf++)
      #pragma unroll
      for (int e4 = 0; e4 < 4; e4++) {
        float v = acc[nf][e4] + b1v[nf];
        bnc[w*1024 + (lk*4+e4)*64 + nf*16 + lm] = (v >= 1.2f) ? 1 : 0;
      }
    const int pxl = l >> 2, coq = l & 3;
    i32x4 sp = *(const i32x4*)(bnc + w*1024 + pxl*64 + coq*16);
    const int gcol = colh*16 + pxl;
    const int cq = coq ^ SWZ(gcol + 1);
    *(i32x4*)(S8b + (size_t)(row*32 + gcol)*64 + cq*16) = sp;
  }
}

// ---- conv2 + LIF + count. 256 blocks (b, row-quarter of 8 rows), 512 thr = 8 waves.
// wave: 2 out-rows x 32 co (ch = wv>>2, row-pair = wv&3). B-frags persistent in VGPRs.
// A-tile [10 rows][34 cols][64 ci] double-buffered in LDS; t+1 prefetched via
// global_load_lds while computing t; pad cols/rows zeroed once at start.
__global__ __launch_bounds__(512, 2) void conv2_k(
    const unsigned char* __restrict__ S8, const signed char* __restrict__ Bq,
    const float* __restrict__ b2, unsigned char* __restrict__ cnt)
{
  __shared__ __align__(16) unsigned char Abuf[2][21760];   // [buf][10*2176]
  const int j  = blockIdx.x;
  const int b  = ((j >> 3) & 7) * 8 + (j & 7);   // b%8 == j%8 == conv1's XCD
  const int rq = j >> 6;                         // 0..3 row-quarter
  const int tid = threadIdx.x;
  const int wv = tid >> 6, l = tid & 63;
  const int lm = l & 15, lk = l >> 4;
  const int ch = wv >> 2;                        // co half (0/1)
  const int wr = wv & 3;                         // out-row pair within the 8-row slice

  // persistent B fragments: [q][s][nf], 36 x i32x4 = 144 VGPR
  i32x4 Bf[2][9][2];
  #pragma unroll
  for (int q = 0; q < 2; q++)
    #pragma unroll
    for (int s = 0; s < 9; s++)
      #pragma unroll
      for (int nf = 0; nf < 2; nf++)
        Bf[q][s][nf] = *(const i32x4*)(Bq + q*36864 + s*4096 + (ch*32+nf*16+lm)*64 + lk*16);
  const float b2v[2] = { b2[ch*32 + lm], b2[ch*32 + 16 + lm] };

  // zero both LDS buffers (pad cols 0/33 + edge rows stay zero; interior re-staged per t)
  {
    i32x4 z = {0,0,0,0};
    i32x4* ap = (i32x4*)Abuf;
    #pragma unroll
    for (int it = 0; it < 6; it++) { int c = it*512 + tid; if (c < 2720) ap[c] = z; }
  }
  __syncthreads();

  // stage t=0 into buf0: waves 0..4 stage LDS rows {2w,2w+1}; rows outside image skipped
  {
    const unsigned char* Simg = S8 + (size_t)(0*64 + b)*SZ_IMG;
    if (wv < 5) {
      #pragma unroll
      for (int rr = 0; rr < 2; rr++) {
        const int lr = wv*2 + rr;
        const int grow = rq*8 - 1 + lr;
        if (grow >= 0 && grow < 32) {
          const unsigned char* src = Simg + grow*2048 + l*16;
          unsigned char* dst = &Abuf[0][lr*2176 + 64];
          gl_lds16(src, dst);
          gl_lds16(src + 1024, dst + 1024);
        }
      }
    }
  }
  __syncthreads();   // drains vmcnt -> buf0 ready

  unsigned int cntp[4][2] = {};

  for (int t = 0; t < 8; t++) {
    // prefetch t+1 into the other buffer (issued before compute; lands during it)
    if (t < 7 && wv < 5) {
      const unsigned char* Simg = S8 + (size_t)((t+1)*64 + b)*SZ_IMG;
      unsigned char* bufn = Abuf[(t+1) & 1];
      #pragma unroll
      for (int rr = 0; rr < 2; rr++) {
        const int lr = wv*2 + rr;
        const int grow = rq*8 - 1 + lr;
        if (grow >= 0 && grow < 32) {
          const unsigned char* src = Simg + grow*2048 + l*16;
          unsigned char* dst = bufn + lr*2176 + 64;
          gl_lds16(src, dst);
          gl_lds16(src + 1024, dst + 1024);
        }
      }
    }

    const unsigned char* ab = Abuf[t & 1];
    i32x4 acc1[4][2] = {}, acc2[4][2] = {};
    #pragma unroll
    for (int s = 0; s < 9; s++) {
      const int dr = s/3, dc = s - dr*3;
      #pragma unroll
      for (int a = 0; a < 4; a++) {
        const int lr = 2*wr + (a>>1) + dr;            // LDS row 0..9
        const int cp = ((a&1)<<4) + lm + dc;          // LDS col 0..33
        i32x4 Af = *(const i32x4*)(ab + lr*2176 + cp*64 + ((lk ^ SWZ(cp)) << 4));
        #pragma unroll
        for (int nf = 0; nf < 2; nf++) {
          acc1[a][nf] = __builtin_amdgcn_mfma_i32_16x16x64_i8(Af, Bf[0][s][nf], acc1[a][nf],0,0,0);
          acc2[a][nf] = __builtin_amdgcn_mfma_i32_16x16x64_i8(Af, Bf[1][s][nf], acc2[a][nf],0,0,0);
        }
      }
    }

    #pragma unroll
    for (int a = 0; a < 4; a++)
      #pragma unroll
      for (int nf = 0; nf < 2; nf++) {
        unsigned int p = 0;
        #pragma unroll
        for (int e = 0; e < 4; e++) {
          float v = S1Q*(float)acc1[a][nf][e] + S2Q*(float)acc2[a][nf][e] + b2v[nf];
          p |= (v >= 1.2f ? 1u : 0u) << (8*e);
        }
        cntp[a][nf] += p;                   // counts <= 8 per byte, no carry
      }
    __syncthreads();   // drains vmcnt (t+1 staged) + all waves done reading buf[t&1]
  }

  // cnt store via LDS bounce -> full-line 16B writes. bounce[co][or*32+col] = 16 KB
  unsigned char* bb = (unsigned char*)Abuf;
  #pragma unroll
  for (int a = 0; a < 4; a++) {
    const int orow = 2*wr + (a>>1);
    const int colb = ((a&1)<<4) + lk*4;
    #pragma unroll
    for (int nf = 0; nf < 2; nf++) {
      const int co = ch*32 + nf*16 + lm;
      *(unsigned int*)(bb + co*256 + orow*32 + colb) = cntp[a][nf];
    }
  }
  __syncthreads();
  #pragma unroll
  for (int it = 0; it < 2; it++) {
    const int c = it*512 + tid;              // 0..1023 chunks of 16B
    const int co = c >> 4, inner = (c & 15) << 4;
    *(i32x4*)(cnt + (size_t)(b*64 + co)*1024 + rq*256 + inner) =
        *(const i32x4*)(bb + co*256 + inner);
  }
}

// ---- FC: out[b,o] = sum_i cnt[b,i]*wfc[o,i] + 8*bfc[o]
__global__ __launch_bounds__(256) void fc_k(
    const unsigned char* __restrict__ cnt, const float* __restrict__ wfc,
    const float* __restrict__ bfc, float* __restrict__ out)
{
  const int b = blockIdx.x & 63;
  const int chunk = blockIdx.x >> 6;
  const int tid = threadIdx.x;
  float acc[10];
  #pragma unroll
  for (int o = 0; o < 10; o++) acc[o] = 0.f;
  const int i4base = chunk*4096 + tid;
  for (int w = 0; w < 16; w++) {
    int i4 = i4base + w*256;
    uchar4 cv = *(const uchar4*)(cnt + (size_t)b*65536 + i4*4);
    float c0 = cv.x, c1 = cv.y, c2 = cv.z, c3 = cv.w;
    #pragma unroll
    for (int o = 0; o < 10; o++) {
      float4 wv = *(const float4*)(wfc + (size_t)o*65536 + i4*4);
      acc[o] += wv.x*c0 + wv.y*c1 + wv.z*c2 + wv.w*c3;
    }
  }
  __shared__ float red[10][256];
  #pragma unroll
  for (int o = 0; o < 10; o++) red[o][tid] = acc[o];
  __syncthreads();
  for (int off = 128; off > 0; off >>= 1) {
    if (tid < off) {
      #pragma unroll
      for (int o = 0; o < 10; o++) red[o][tid] += red[o][tid + off];
    }
    __syncthreads();
  }
  if (tid < 10) {
    float v = red[tid][0];
    if (chunk == 0) v += 8.0f * bfc[tid];
    atomicAdd(out + b*10 + tid, v);
  }
}

extern "C" void kernel_launch(void* const* d_in, const int* in_sizes, int n_in,
                              void* d_out, int out_size, void* d_ws, size_t ws_size,
                              hipStream_t stream)
{
  const float* x   = (const float*)d_in[0];
  const float* w1  = (const float*)d_in[1];
  const float* b1  = (const float*)d_in[2];
  const float* w2  = (const float*)d_in[3];
  const float* b2  = (const float*)d_in[4];
  const float* wfc = (const float*)d_in[5];
  const float* bfc = (const float*)d_in[6];
  float* out = (float*)d_out;

  unsigned char* ws  = (unsigned char*)d_ws;
  unsigned char* S8  = ws + OFF_S8;
  unsigned char* cnt = ws + OFF_CNT;
  short*         W1F = (short*)(ws + OFF_W1F);
  signed char*   Bq  = (signed char*)(ws + OFF_BQ);

  hipMemsetAsync(out, 0, 64*10*sizeof(float), stream);
  kprep<<<144, 256, 0, stream>>>(w1, w2, W1F, Bq);
  conv1_k<<<512, 256, 0, stream>>>(x, W1F, b1, S8);
  conv2_k<<<256, 512, 0, stream>>>(S8, Bq, b2, cnt);
  fc_k<<<256, 256, 0, stream>>>(cnt, wfc, bfc, out);
}